// Round 3
// baseline (864.828 us; speedup 1.0000x reference)
//
#include <hip/hip_runtime.h>
#include <hip/hip_bf16.h>

typedef unsigned int u32;

// ---------------- CSR build ----------------
__global__ __launch_bounds__(256) void count_deg(const int* __restrict__ dst, int* __restrict__ deg, int E, int N){
  int e = blockIdx.x*256 + threadIdx.x;
  if(e < E){
    int d = dst[e];
    if((u32)d >= (u32)N) d = 0;
    atomicAdd(&deg[d], 1);
  }
}

__global__ __launch_bounds__(256) void scan_block(const int* __restrict__ deg, int* __restrict__ offs,
                                                  int* __restrict__ bsum, int n){
  __shared__ int s[256];
  int i = blockIdx.x*256 + threadIdx.x;
  int v = (i<n) ? deg[i] : 0;
  s[threadIdx.x] = v; __syncthreads();
  #pragma unroll
  for(int d=1; d<256; d<<=1){
    int t = (threadIdx.x>=d) ? s[threadIdx.x-d] : 0;
    __syncthreads();
    s[threadIdx.x] += t;
    __syncthreads();
  }
  if(i<n) offs[i] = s[threadIdx.x] - v;
  if(threadIdx.x==255) bsum[blockIdx.x] = s[255];
}

__global__ __launch_bounds__(256) void scan_bsum(int* __restrict__ bsum, int nb){
  __shared__ int s[256];
  int v = (threadIdx.x<nb) ? bsum[threadIdx.x] : 0;
  s[threadIdx.x]=v; __syncthreads();
  #pragma unroll
  for(int d=1; d<256; d<<=1){
    int t = (threadIdx.x>=d) ? s[threadIdx.x-d] : 0;
    __syncthreads();
    s[threadIdx.x] += t;
    __syncthreads();
  }
  if(threadIdx.x<nb) bsum[threadIdx.x] = s[threadIdx.x] - v;
}

__global__ __launch_bounds__(256) void scan_add(int* __restrict__ offs, const int* __restrict__ bsum,
                                                int* __restrict__ cursor, int n, int E){
  int i = blockIdx.x*256 + threadIdx.x;
  if(i<n){
    int o = offs[i] + bsum[blockIdx.x];
    offs[i]=o; cursor[i]=o;
  }
  if(i==0) offs[n]=E;
}

__global__ __launch_bounds__(256) void fill_edges(const int* __restrict__ src, const int* __restrict__ dst,
                                                  int* __restrict__ cursor, int* __restrict__ elist, int E, int N){
  int e = blockIdx.x*256 + threadIdx.x;
  if(e<E){
    int d = dst[e];
    if((u32)d >= (u32)N) d = 0;
    int s = src[e];
    if((u32)s >= (u32)N) s = 0;
    int p = atomicAdd(&cursor[d], 1);
    if((u32)p < (u32)E) elist[p] = s;
  }
}

// h0[i] = x[i] + sum_{j->i} x[j]   (all fp32). 32 lanes per node row of 128.
__global__ __launch_bounds__(256) void gather_sum(const float* __restrict__ x, const int* __restrict__ offs,
                                                  const int* __restrict__ elist, float* __restrict__ h0,
                                                  int N, int E){
  int slot = threadIdx.x >> 5;
  int c = threadIdx.x & 31;
  int i = blockIdx.x*8 + slot;
  if(i >= N) return;
  const float4* xr = (const float4*)x;
  float4 acc = xr[(size_t)i*32 + c];
  int e0 = offs[i], e1 = offs[i+1];
  e0 = max(0, min(e0, E));
  e1 = max(e0, min(e1, E));
  for(int j=e0; j<e1; j++){
    int s = elist[j];
    if((u32)s >= (u32)N) s = 0;
    float4 v = xr[(size_t)s*32 + c];
    acc.x += v.x; acc.y += v.y; acc.z += v.z; acc.w += v.w;
  }
  ((float4*)h0)[(size_t)i*32 + c] = acc;
}

// ---------------- fp32 tiled GEMM: C[M,256] = op(A[M,K]) @ B[K,256] + bias ----------------
// tile 64x256, 256 threads, 8x8 micro-tile (rows/cols split 4+4 for b128 LDS reads)
template<int K, bool BNA, bool RELUOUT>
__global__ __launch_bounds__(256) void gemm_k(const float* __restrict__ A, const float* __restrict__ B,
                                              const float* __restrict__ bias,
                                              const float* __restrict__ scale, const float* __restrict__ shift,
                                              float* __restrict__ C, int M){
  __shared__ float As[16][64];
  __shared__ float Bs[16][256];
  const int tid = threadIdx.x;
  const int tn = tid & 31, tm = tid >> 5;
  const int m0 = blockIdx.x * 64;
  float acc[8][8];
  #pragma unroll
  for(int i=0;i<8;i++){
    #pragma unroll
    for(int j=0;j<8;j++) acc[i][j]=0.f;
  }
  const int arow = tid >> 2;          // 0..63
  const int akk  = (tid & 3)*4;       // 0,4,8,12
  const int brow = tid >> 6;          // 0..3
  const int bn4  = (tid & 63)*4;      // 0..252

  for(int k0=0; k0<K; k0+=16){
    float4 a4 = make_float4(0.f,0.f,0.f,0.f);
    if(m0 + arow < M) a4 = *(const float4*)(A + (size_t)(m0+arow)*K + k0 + akk);
    if(BNA){
      float4 s4 = *(const float4*)(scale + k0 + akk);
      float4 t4 = *(const float4*)(shift + k0 + akk);
      a4.x = fmaxf(fmaf(s4.x, a4.x, t4.x), 0.f);
      a4.y = fmaxf(fmaf(s4.y, a4.y, t4.y), 0.f);
      a4.z = fmaxf(fmaf(s4.z, a4.z, t4.z), 0.f);
      a4.w = fmaxf(fmaf(s4.w, a4.w, t4.w), 0.f);
    }
    As[akk+0][arow]=a4.x; As[akk+1][arow]=a4.y; As[akk+2][arow]=a4.z; As[akk+3][arow]=a4.w;
    #pragma unroll
    for(int p=0;p<4;p++){
      int kr = brow + p*4;
      *(float4*)&Bs[kr][bn4] = *(const float4*)(B + (size_t)(k0+kr)*256 + bn4);
    }
    __syncthreads();
    #pragma unroll
    for(int k=0;k<16;k++){
      float4 a0 = *(const float4*)&As[k][tm*4];
      float4 a1 = *(const float4*)&As[k][32 + tm*4];
      float4 b0 = *(const float4*)&Bs[k][tn*4];
      float4 b1 = *(const float4*)&Bs[k][128 + tn*4];
      float ar[8] = {a0.x,a0.y,a0.z,a0.w,a1.x,a1.y,a1.z,a1.w};
      float br[8] = {b0.x,b0.y,b0.z,b0.w,b1.x,b1.y,b1.z,b1.w};
      #pragma unroll
      for(int i=0;i<8;i++){
        #pragma unroll
        for(int j=0;j<8;j++) acc[i][j] = fmaf(ar[i], br[j], acc[i][j]);
      }
    }
    __syncthreads();
  }
  float bb[8];
  {
    float4 t0 = *(const float4*)(bias + tn*4);
    float4 t1 = *(const float4*)(bias + 128 + tn*4);
    bb[0]=t0.x; bb[1]=t0.y; bb[2]=t0.z; bb[3]=t0.w;
    bb[4]=t1.x; bb[5]=t1.y; bb[6]=t1.z; bb[7]=t1.w;
  }
  #pragma unroll
  for(int i=0;i<8;i++){
    int row = m0 + ((i<4) ? (tm*4+i) : (32 + tm*4 + (i-4)));
    if(row < M){
      float4 o0, o1;
      o0.x=acc[i][0]+bb[0]; o0.y=acc[i][1]+bb[1]; o0.z=acc[i][2]+bb[2]; o0.w=acc[i][3]+bb[3];
      o1.x=acc[i][4]+bb[4]; o1.y=acc[i][5]+bb[5]; o1.z=acc[i][6]+bb[6]; o1.w=acc[i][7]+bb[7];
      if(RELUOUT){
        o0.x=fmaxf(o0.x,0.f); o0.y=fmaxf(o0.y,0.f); o0.z=fmaxf(o0.z,0.f); o0.w=fmaxf(o0.w,0.f);
        o1.x=fmaxf(o1.x,0.f); o1.y=fmaxf(o1.y,0.f); o1.z=fmaxf(o1.z,0.f); o1.w=fmaxf(o1.w,0.f);
      }
      *(float4*)(C + (size_t)row*256 + tn*4)       = o0;
      *(float4*)(C + (size_t)row*256 + 128 + tn*4) = o1;
    }
  }
}

// ---------------- BN stats ----------------
__global__ __launch_bounds__(256) void col_stats(const float* __restrict__ h, float* __restrict__ sums,
                                                 int M, int rowsPerBlock){
  int t = threadIdx.x;
  int r0 = blockIdx.x * rowsPerBlock;
  int r1 = min(r0 + rowsPerBlock, M);
  float s=0.f, q=0.f;
  for(int r=r0; r<r1; r++){
    float v = h[(size_t)r*256 + t];
    s += v; q = fmaf(v, v, q);
  }
  atomicAdd(&sums[t], s);
  atomicAdd(&sums[256+t], q);
}

__global__ void bn_fin(const float* __restrict__ sums, const float* __restrict__ gamma,
                       const float* __restrict__ beta, float* __restrict__ scale,
                       float* __restrict__ shift, float invM){
  int t = threadIdx.x;
  float mu  = sums[t]*invM;
  float var = fmaxf(sums[256+t]*invM - mu*mu, 0.f);
  float sc  = gamma[t] * rsqrtf(var + 1e-5f);
  scale[t] = sc;
  shift[t] = fmaf(-mu, sc, beta[t]);
}

// ---------------- gate: one wave per node ----------------
__global__ __launch_bounds__(256) void gate_k(const float* __restrict__ h2, const float* __restrict__ Wg,
                                              const float* __restrict__ bg, float* __restrict__ gate, int N){
  int gw = (blockIdx.x*256 + threadIdx.x) >> 6;
  int l  = threadIdx.x & 63;
  if(gw >= N) return;
  float4 v = *(const float4*)(h2 + (size_t)gw*256 + l*4);
  float4 w = *(const float4*)(Wg + l*4);
  float p = v.x*w.x + v.y*w.y + v.z*w.z + v.w*w.w;
  #pragma unroll
  for(int d=32; d>0; d>>=1) p += __shfl_down(p, d, 64);
  if(l==0) gate[gw] = p + bg[0];
}

// ---------------- attentional pool: one block per graph (batch sorted) ----------------
__global__ __launch_bounds__(256) void pool_k(const float* __restrict__ h2, const float* __restrict__ gate,
                                              const int* __restrict__ batch, float* __restrict__ pooled, int N){
  int g = blockIdx.x;
  __shared__ int sb[2];
  __shared__ float red[4];
  __shared__ float s_m, s_inv;
  if(threadIdx.x < 2){
    int target = g + threadIdx.x;
    int lo=0, hi=N;
    while(lo<hi){ int mid=(lo+hi)>>1; if(batch[mid] < target) lo=mid+1; else hi=mid; }
    sb[threadIdx.x] = lo;
  }
  __syncthreads();
  int beg = sb[0], end = sb[1];
  // pass 1: segment max
  float mx = -1e30f;
  for(int i=beg+threadIdx.x; i<end; i+=256) mx = fmaxf(mx, gate[i]);
  #pragma unroll
  for(int d=32; d>0; d>>=1) mx = fmaxf(mx, __shfl_down(mx, d, 64));
  if((threadIdx.x&63)==0) red[threadIdx.x>>6] = mx;
  __syncthreads();
  if(threadIdx.x==0) s_m = fmaxf(fmaxf(red[0],red[1]), fmaxf(red[2],red[3]));
  __syncthreads();
  float m = s_m;
  // pass 2: sum exp(g-m)
  float s = 0.f;
  for(int i=beg+threadIdx.x; i<end; i+=256) s += expf(gate[i]-m);
  #pragma unroll
  for(int d=32; d>0; d>>=1) s += __shfl_down(s, d, 64);
  if((threadIdx.x&63)==0) red[threadIdx.x>>6] = s;
  __syncthreads();
  if(threadIdx.x==0){
    float tot = red[0]+red[1]+red[2]+red[3];
    s_inv = (tot > 0.f) ? 1.f/tot : 0.f;
  }
  __syncthreads();
  float inv = s_inv;
  int t = threadIdx.x;
  float acc = 0.f;
  for(int i=beg; i<end; i++){
    float a = expf(gate[i]-m) * inv;
    acc = fmaf(a, h2[(size_t)i*256 + t], acc);
  }
  pooled[g*256 + t] = acc;
}

// ---------------- head BN (G rows, single block of 256) ----------------
__global__ void bn2_k(const float* __restrict__ pooled, const float* __restrict__ g2,
                      const float* __restrict__ be2, float* __restrict__ sc2,
                      float* __restrict__ sh2, int G){
  int t = threadIdx.x;
  float s=0.f, q=0.f;
  for(int r=0; r<G; r++){ float v = pooled[r*256+t]; s+=v; q=fmaf(v,v,q); }
  float invG = 1.f/(float)G;
  float mu = s*invG;
  float var = fmaxf(q*invG - mu*mu, 0.f);
  float sc = g2[t] * rsqrtf(var + 1e-5f);
  sc2[t]=sc; sh2[t]=fmaf(-mu, sc, be2[t]);
}

// ---------------- head linear + log_softmax: one wave per graph ----------------
__global__ __launch_bounds__(256) void head_k(const float* __restrict__ pooled,
                                              const float* __restrict__ sc2, const float* __restrict__ sh2,
                                              const float* __restrict__ Wh, const float* __restrict__ bh,
                                              float* __restrict__ out, int G){
  int w = (blockIdx.x*256 + threadIdx.x) >> 6;
  int l = threadIdx.x & 63;
  if(w >= G) return;
  float4 v  = *(const float4*)(pooled + (size_t)w*256 + l*4);
  float4 sc = *(const float4*)(sc2 + l*4);
  float4 sh = *(const float4*)(sh2 + l*4);
  float vv[4] = { fmaf(sc.x,v.x,sh.x), fmaf(sc.y,v.y,sh.y), fmaf(sc.z,v.z,sh.z), fmaf(sc.w,v.w,sh.w) };
  float4 w0 = *(const float4*)(Wh + (size_t)l*8);      // rows 4l,4l+1 (2 cols each)
  float4 w1 = *(const float4*)(Wh + (size_t)l*8 + 4);  // rows 4l+2,4l+3
  float a0 = vv[0]*w0.x + vv[1]*w0.z + vv[2]*w1.x + vv[3]*w1.z;
  float a1 = vv[0]*w0.y + vv[1]*w0.w + vv[2]*w1.y + vv[3]*w1.w;
  #pragma unroll
  for(int d=32; d>0; d>>=1){ a0 += __shfl_down(a0,d,64); a1 += __shfl_down(a1,d,64); }
  if(l==0){
    float z0 = a0 + bh[0];
    float z1 = a1 + bh[1];
    float mz = fmaxf(z0,z1);
    float lse = mz + logf(expf(z0-mz) + expf(z1-mz));
    out[w*2]   = z0 - lse;
    out[w*2+1] = z1 - lse;
  }
}

extern "C" void kernel_launch(void* const* d_in, const int* in_sizes, int n_in,
                              void* d_out, int out_size, void* d_ws, size_t ws_size,
                              hipStream_t stream){
  const float* x   = (const float*)d_in[0];
  const int*   ei  = (const int*)d_in[1];
  const int*   bat = (const int*)d_in[2];
  const float* W1  = (const float*)d_in[3];
  const float* b1  = (const float*)d_in[4];
  const float* g1  = (const float*)d_in[5];
  const float* be1 = (const float*)d_in[6];
  const float* W2  = (const float*)d_in[7];
  const float* b2  = (const float*)d_in[8];
  const float* Wg  = (const float*)d_in[9];
  const float* bg  = (const float*)d_in[10];
  const float* g2  = (const float*)d_in[11];
  const float* be2 = (const float*)d_in[12];
  const float* Wh  = (const float*)d_in[13];
  const float* bh  = (const float*)d_in[14];

  const int N = in_sizes[0] / 128;   // 50000
  const int E = in_sizes[1] / 2;     // 1600000
  const int G = out_size / 2;        // 512

  // ---- workspace layout (~103.2 MB) ----
  // region A [0, 51.2MB): phase1 {h0 fp32 25.6MB, elist 6.4MB, offs/deg/cursor/bsum}
  //                       phase2 {h2 fp32 51.2MB} (phase-1 data dead by then)
  char* ws = (char*)d_ws;
  float* h0    = (float*)ws;                         // 25,600,000 B
  int*   elist = (int*)(ws + 25600000);              //  6,400,000 B
  int*   offs  = (int*)(ws + 32000000);              //    200,004 B
  int*   deg   = (int*)(ws + 32200192);              //    200,000 B
  int*   cursor= (int*)(ws + 32400384);              //    200,000 B
  int*   bsum  = (int*)(ws + 32600576);              //      1,024 B
  float* h2    = (float*)ws;                         // 51,200,000 B (phase2)
  float* h1    = (float*)(ws + 51200000);            // 51,200,000 B
  char*  p2 = ws + 102400000;
  float* sums1 = (float*)p2;          p2 += 2048;
  float* sc1   = (float*)p2;          p2 += 1024;
  float* sh1   = (float*)p2;          p2 += 1024;
  float* gate  = (float*)p2;          p2 += (size_t)N*4 + 256;
  float* pooled= (float*)p2;          p2 += (size_t)G*256*4;
  float* sc2   = (float*)p2;          p2 += 1024;
  float* sh2   = (float*)p2;          p2 += 1024;

  const int* src = ei;
  const int* dst = ei + E;

  hipMemsetAsync(deg, 0, (size_t)N*4, stream);
  hipMemsetAsync(sums1, 0, 512*4, stream);

  int nscan = (N + 255)/256;
  count_deg  <<<(E+255)/256, 256, 0, stream>>>(dst, deg, E, N);
  scan_block <<<nscan, 256, 0, stream>>>(deg, offs, bsum, N);
  scan_bsum  <<<1, 256, 0, stream>>>(bsum, nscan);
  scan_add   <<<nscan, 256, 0, stream>>>(offs, bsum, cursor, N, E);
  fill_edges <<<(E+255)/256, 256, 0, stream>>>(src, dst, cursor, elist, E, N);
  gather_sum <<<(N+7)/8, 256, 0, stream>>>(x, offs, elist, h0, N, E);

  gemm_k<128,false,false><<<(N+63)/64, 256, 0, stream>>>(h0, W1, b1, nullptr, nullptr, h1, N);
  col_stats  <<<100, 256, 0, stream>>>(h1, sums1, N, (N+99)/100);
  bn_fin     <<<1, 256, 0, stream>>>(sums1, g1, be1, sc1, sh1, 1.0f/(float)N);
  gemm_k<256,true,true><<<(N+63)/64, 256, 0, stream>>>(h1, W2, b2, sc1, sh1, h2, N);

  gate_k <<<(N+3)/4, 256, 0, stream>>>(h2, Wg, bg, gate, N);
  pool_k <<<G, 256, 0, stream>>>(h2, gate, bat, pooled, N);
  bn2_k  <<<1, 256, 0, stream>>>(pooled, g2, be2, sc2, sh2, G);
  head_k <<<(G+3)/4, 256, 0, stream>>>(pooled, sc2, sh2, Wh, bh, (float*)d_out, G);
}